// Round 11
// baseline (194.663 us; speedup 1.0000x reference)
//
#include <hip/hip_runtime.h>
#include <hip/hip_bf16.h>
#include <math.h>

#define NSENT 65536
#define NBAGS 4096
#define DIM 768
#define D4 192            // float4 / ushort4 per row
#define FLATC 53
#define CPAD 64           // padded class count for probs MFMA
#define KTOT 2304         // 3*DIM
#define K4 576            // KTOT/4
#define CH 16             // sentences per LDS chunk

typedef short bf16x8 __attribute__((ext_vector_type(8)));
typedef float f32x4 __attribute__((ext_vector_type(4)));

__device__ __forceinline__ float wsum(float v) {
#pragma unroll
  for (int o = 32; o; o >>= 1) v += __shfl_xor(v, o);
  return v;
}
__device__ __forceinline__ float wmax(float v) {
#pragma unroll
  for (int o = 32; o; o >>= 1) v = fmaxf(v, __shfl_xor(v, o));
  return v;
}
__device__ __forceinline__ float dot4(float4 a, float4 b) {
  return a.x * b.x + a.y * b.y + a.z * b.z + a.w * b.w;
}
__device__ __forceinline__ unsigned short f2bf(float f) {
  union { __hip_bfloat16 b; unsigned short s; } cv;
  cv.b = __float2bfloat16(f);
  return cv.s;
}
__device__ __forceinline__ float bf2f(unsigned short s) {
  return __uint_as_float(((unsigned int)s) << 16);
}
__device__ __forceinline__ ushort4 pk4(float4 v) {
  ushort4 h;
  h.x = f2bf(v.x); h.y = f2bf(v.y); h.z = f2bf(v.z); h.w = f2bf(v.w);
  return h;
}
__device__ __forceinline__ float4 up4(ushort4 h) {
  return make_float4(bf2f(h.x), bf2f(h.y), bf2f(h.z), bf2f(h.w));
}

// ---- K1: relation_weight f32[53][2304] -> bf16 padded [64][2304] ----
__global__ __launch_bounds__(256) void rwcvt(const float* __restrict__ rw,
                                             unsigned short* __restrict__ rw16) {
  const int idx = blockIdx.x * 256 + threadIdx.x;
  if (idx < CPAD * KTOT) {
    const int row = idx / KTOT;
    rw16[idx] = f2bf(row < FLATC ? rw[idx] : 0.f);
  }
}

// ---- K2: FUSED per-bag logits + softmax + weighted sum ----
// Block per bag, 192 threads = 3 waves (bag_sum's proven shape).
// x rows staged ONCE per chunk into LDS as bf16 and consumed by both
// the logit phase and the aggregation phase -> single global x pass.
__global__ __launch_bounds__(192) void fused_bag(
    const float* __restrict__ x, const int* __restrict__ q,
    const float* __restrict__ aw, const int* __restrict__ scope,
    float* __restrict__ out, unsigned short* __restrict__ lt16) {
  const int b = blockIdx.x;
  const int s0 = scope[b];
  const int s1 = scope[b + 1];
  const int len = s1 - s0;
  const int tid = threadIdx.x;
  const int wave = tid >> 6;   // 0..2
  const int lane = tid & 63;

  __shared__ ushort4 xs[CH * D4];  // 24 KB bf16 x chunk
  __shared__ float lg[CH][3];
  __shared__ float sm[3], se[3];

  float m[3] = {-INFINITY, -INFINITY, -INFINITY};
  float dsum[3] = {0.f, 0.f, 0.f};
  float4 acc[3];
#pragma unroll
  for (int l = 0; l < 3; l++) acc[l] = make_float4(0.f, 0.f, 0.f, 0.f);

  const float4* __restrict__ X4 = (const float4*)x;
  const float4* __restrict__ AW4 = (const float4*)aw;

  for (int cs = 0; cs < len; cs += CH) {
    const int clen = min(CH, len - cs);

    // ---- stage x chunk -> LDS bf16 (coalesced, 4 loads in flight) ----
    {
      int i = 0;
      for (; i + 4 <= clen; i += 4) {
        float4 v0 = X4[(size_t)(s0 + cs + i + 0) * D4 + tid];
        float4 v1 = X4[(size_t)(s0 + cs + i + 1) * D4 + tid];
        float4 v2 = X4[(size_t)(s0 + cs + i + 2) * D4 + tid];
        float4 v3 = X4[(size_t)(s0 + cs + i + 3) * D4 + tid];
        xs[(i + 0) * D4 + tid] = pk4(v0);
        xs[(i + 1) * D4 + tid] = pk4(v1);
        xs[(i + 2) * D4 + tid] = pk4(v2);
        xs[(i + 3) * D4 + tid] = pk4(v3);
      }
      for (; i < clen; i++)
        xs[i * D4 + tid] = pk4(X4[(size_t)(s0 + cs + i) * D4 + tid]);
    }
    __syncthreads();

    // ---- Phase A: logits from LDS (wave per sentence) ----
    for (int i = wave; i < clen; i += 3) {
      const int n = s0 + cs + i;
      const int q0 = q[3 * n + 0];
      const int q1 = q[3 * n + 1];
      const int q2 = q[3 * n + 2];
      const float4* A0 = AW4 + (size_t)q0 * D4;
      const float4* A1 = AW4 + (size_t)q1 * D4;
      const float4* A2 = AW4 + (size_t)q2 * D4;
      float p0 = 0.f, p1 = 0.f, p2 = 0.f;
#pragma unroll
      for (int j = 0; j < 3; j++) {
        const int c = lane + 64 * j;
        const float4 xv = up4(xs[i * D4 + c]);
        p0 += dot4(xv, A0[c]);
        p1 += dot4(xv, A1[c]);
        p2 += dot4(xv, A2[c]);
      }
      p0 = wsum(p0); p1 = wsum(p1); p2 = wsum(p2);
      if (lane == 0) { lg[i][0] = p0; lg[i][1] = p1; lg[i][2] = p2; }
    }
    __syncthreads();

    // ---- chunk softmax stats (wave l handles layer l) ----
    {
      const int l = wave;
      float cm = -INFINITY;
      for (int i = lane; i < clen; i += 64) cm = fmaxf(cm, lg[i][l]);
      cm = wmax(cm);
      const float mn = fmaxf(m[l], cm);
      float es = 0.f;
      for (int i = lane; i < clen; i += 64) {
        const float e = __expf(lg[i][l] - mn);
        es += e;
        lg[i][l] = e;  // unnormalized weight
      }
      es = wsum(es);
      if (lane == 0) { sm[l] = mn; se[l] = es; }
    }
    __syncthreads();

    // ---- rescale running state ----
#pragma unroll
    for (int l = 0; l < 3; l++) {
      const float mn = sm[l];
      const float sc = __expf(m[l] - mn);  // exp(-inf)=0 first chunk
      m[l] = mn;
      dsum[l] = dsum[l] * sc + se[l];
      acc[l].x *= sc; acc[l].y *= sc; acc[l].z *= sc; acc[l].w *= sc;
    }

    // ---- Phase B: weighted accumulation from LDS ----
    {
      int i = 0;
      for (; i + 2 <= clen; i += 2) {
        const float w00 = lg[i][0], w01 = lg[i][1], w02 = lg[i][2];
        const float w10 = lg[i + 1][0], w11 = lg[i + 1][1], w12 = lg[i + 1][2];
        const float4 x0 = up4(xs[i * D4 + tid]);
        const float4 x1 = up4(xs[(i + 1) * D4 + tid]);
        acc[0].x += w00 * x0.x + w10 * x1.x;
        acc[0].y += w00 * x0.y + w10 * x1.y;
        acc[0].z += w00 * x0.z + w10 * x1.z;
        acc[0].w += w00 * x0.w + w10 * x1.w;
        acc[1].x += w01 * x0.x + w11 * x1.x;
        acc[1].y += w01 * x0.y + w11 * x1.y;
        acc[1].z += w01 * x0.z + w11 * x1.z;
        acc[1].w += w01 * x0.w + w11 * x1.w;
        acc[2].x += w02 * x0.x + w12 * x1.x;
        acc[2].y += w02 * x0.y + w12 * x1.y;
        acc[2].z += w02 * x0.z + w12 * x1.z;
        acc[2].w += w02 * x0.w + w12 * x1.w;
      }
      if (i < clen) {
        const float a0 = lg[i][0], a1 = lg[i][1], a2 = lg[i][2];
        const float4 xv = up4(xs[i * D4 + tid]);
        acc[0].x += a0 * xv.x; acc[0].y += a0 * xv.y; acc[0].z += a0 * xv.z; acc[0].w += a0 * xv.w;
        acc[1].x += a1 * xv.x; acc[1].y += a1 * xv.y; acc[1].z += a1 * xv.z; acc[1].w += a1 * xv.w;
        acc[2].x += a2 * xv.x; acc[2].y += a2 * xv.y; acc[2].z += a2 * xv.z; acc[2].w += a2 * xv.w;
      }
    }
    __syncthreads();  // protect xs/lg before next chunk
  }

  // ---- finalize: normalize, write stack [3][B][D], lt [B][3D], lt16 ----
  float4* o0 = (float4*)out;
  float4* o1 = (float4*)(out + (size_t)3 * NBAGS * DIM);
  ushort4* l16 = (ushort4*)(lt16 + (size_t)b * KTOT);
#pragma unroll
  for (int l = 0; l < 3; l++) {
    const float inv = (dsum[l] > 0.f) ? (1.f / dsum[l]) : 0.f;
    float4 v = acc[l];
    v.x *= inv; v.y *= inv; v.z *= inv; v.w *= inv;
    o0[((size_t)l * NBAGS + b) * D4 + tid] = v;
    o1[(size_t)b * K4 + l * D4 + tid] = v;
    l16[l * D4 + tid] = pk4(v);
  }
}

// ---- K3: probs = lt @ rw^T + bias via bf16 MFMA (64 bags x 64 classes) ----
__global__ __launch_bounds__(256) void probs_mfma(
    const unsigned short* __restrict__ lt16,
    const unsigned short* __restrict__ rw16,
    const float* __restrict__ bias, float* __restrict__ outp) {
  const int wv = threadIdx.x >> 6;
  const int lane = threadIdx.x & 63;
  const int r = lane & 15;
  const int kg = lane >> 4;
  const int bagbase = blockIdx.x * 64 + wv * 16;

  f32x4 acc[4];
#pragma unroll
  for (int ct = 0; ct < 4; ct++) acc[ct] = (f32x4){0.f, 0.f, 0.f, 0.f};

  const unsigned short* ap = lt16 + (size_t)(bagbase + r) * KTOT + kg * 8;
  const unsigned short* bp[4];
#pragma unroll
  for (int ct = 0; ct < 4; ct++)
    bp[ct] = rw16 + (size_t)(ct * 16 + r) * KTOT + kg * 8;

  for (int k = 0; k < KTOT; k += 32) {
    const bf16x8 a = *(const bf16x8*)(ap + k);
#pragma unroll
    for (int ct = 0; ct < 4; ct++) {
      const bf16x8 bb = *(const bf16x8*)(bp[ct] + k);
      acc[ct] = __builtin_amdgcn_mfma_f32_16x16x32_bf16(a, bb, acc[ct], 0, 0, 0);
    }
  }

  // D mapping (m89-verified): col = lane&15, row = (lane>>4)*4 + reg
#pragma unroll
  for (int ct = 0; ct < 4; ct++) {
    const int col = ct * 16 + r;
    if (col < FLATC) {
      const float bv = bias[col];
#pragma unroll
      for (int reg = 0; reg < 4; reg++) {
        const int bag = bagbase + kg * 4 + reg;
        outp[(size_t)bag * FLATC + col] = acc[ct][reg] + bv;
      }
    }
  }
}

extern "C" void kernel_launch(void* const* d_in, const int* in_sizes, int n_in,
                              void* d_out, int out_size, void* d_ws,
                              size_t ws_size, hipStream_t stream) {
  const float* x = (const float*)d_in[0];
  const int* aq = (const int*)d_in[1];
  const int* scope = (const int*)d_in[2];
  const float* aw = (const float*)d_in[3];
  const float* rw = (const float*)d_in[4];
  const float* bias = (const float*)d_in[5];
  float* out = (float*)d_out;

  unsigned short* lt16 = (unsigned short*)d_ws;        // 4096*2304 bf16
  unsigned short* rw16 = lt16 + (size_t)NBAGS * KTOT;  // 64*2304 bf16

  hipLaunchKernelGGL(rwcvt, dim3((CPAD * KTOT + 255) / 256), dim3(256), 0,
                     stream, rw, rw16);
  hipLaunchKernelGGL(fused_bag, dim3(NBAGS), dim3(192), 0, stream, x, aq, aw,
                     scope, out, lt16);

  float* probs = out + (size_t)3 * NBAGS * DIM + (size_t)NBAGS * KTOT;
  hipLaunchKernelGGL(probs_mfma, dim3(NBAGS / 64), dim3(256), 0, stream, lt16,
                     rw16, bias, probs);
}